// Round 10
// baseline (594.218 us; speedup 1.0000x reference)
//
#include <hip/hip_runtime.h>
#include <math.h>

// Problem constants (match reference)
#define NV 8192
#define EV 49152
#define KK 15625

typedef __attribute__((ext_vector_type(8))) short bf16x8;
typedef __attribute__((ext_vector_type(4))) float f32x4;

__device__ __forceinline__ void atomAddF(float* p, float v) {
    unsafeAtomicAdd(p, v);  // native global_atomic_add_f32
}

__device__ __forceinline__ unsigned short bf16rne(float x) {
    unsigned u = __float_as_uint(x);
    unsigned r = u + 0x7FFFu + ((u >> 16) & 1u);
    return (unsigned short)(r >> 16);
}
__device__ __forceinline__ float bf16tof(unsigned short h) {
    return __uint_as_float(((unsigned)h) << 16);
}

__device__ __forceinline__ void edge_frac(const float* __restrict__ pseudo, int e,
                                          float f[3], int lo[3]) {
#pragma unroll
    for (int j = 0; j < 3; ++j) {
        float v = pseudo[e * 3 + j] * 24.0f;
        float fl = floorf(v);
        int l = (int)fl;
        l = l < 0 ? 0 : (l > 23 ? 23 : l);
        lo[j] = l;
        f[j] = v - (float)l;
    }
}

// Prep: transform x -> h0, zero counts + agg.
__global__ void prep_kernel(const float* __restrict__ x, float* __restrict__ h0,
                            int* __restrict__ counts, float* __restrict__ agg) {
    int gt = blockIdx.x * blockDim.x + threadIdx.x;  // grid = NV*64 threads
    if (gt < NV) {
        const float LC = -0.22703196f, UC = 0.36853024f;
        const float LM = 1.2585511f, UM = 1.648841f;
        const float R = 10.0f;
        float t0 = (x[gt * 2 + 0] - LC) / (UC - LC) * (2.0f * R) - R;
        float t1 = (x[gt * 2 + 1] - LM) / (UM - LM) * (2.0f * R) - R;
        h0[gt * 2 + 0] = fminf(fmaxf(t0, -R), R);
        h0[gt * 2 + 1] = fminf(fmaxf(t1, -R), R);
    }
    if (gt < KK) counts[gt] = 0;
    if (gt < NV * 64) agg[gt] = 0.0f;
}

__global__ void hist_kernel(const float* __restrict__ pseudo, int* __restrict__ counts) {
    int e = blockIdx.x * blockDim.x + threadIdx.x;
    if (e >= EV) return;
    float f[3]; int lo[3];
    edge_frac(pseudo, e, f, lo);
#pragma unroll
    for (int s = 0; s < 8; ++s) {
        int wi = (lo[0] + (s & 1)) + 25 * (lo[1] + ((s >> 1) & 1)) + 625 * (lo[2] + ((s >> 2) & 1));
        atomicAdd(&counts[wi], 1);
    }
}

// single-block exclusive scan over KK bins
__global__ void scan_kernel(const int* __restrict__ counts, int* __restrict__ offsets,
                            int* __restrict__ cursor) {
    __shared__ int sums[256];
    const int CH = 62;
    int t = threadIdx.x;
    int base = t * CH;
    int s = 0;
    for (int i = 0; i < CH; ++i) {
        int idx = base + i;
        if (idx < KK) s += counts[idx];
    }
    sums[t] = s;
    __syncthreads();
    for (int d = 1; d < 256; d <<= 1) {
        int v = (t >= d) ? sums[t - d] : 0;
        __syncthreads();
        sums[t] += v;
        __syncthreads();
    }
    int run = (t > 0) ? sums[t - 1] : 0;
    for (int i = 0; i < CH; ++i) {
        int idx = base + i;
        if (idx < KK) {
            offsets[idx] = run;
            cursor[idx] = run;
            run += counts[idx];
        }
    }
    if (t == 255) offsets[KK] = run;
}

// Scatter: pair_src (gather side) and pair_db = {dst, b} (scatter side).
__global__ void scatter_kernel(const float* __restrict__ pseudo, const int* __restrict__ ei,
                               int* __restrict__ cursor,
                               int* __restrict__ pair_src, int2* __restrict__ pair_db) {
    int e = blockIdx.x * blockDim.x + threadIdx.x;
    if (e >= EV) return;
    float f[3]; int lo[3];
    edge_frac(pseudo, e, f, lo);
    int src = ei[e];
    int dst = ei[EV + e];
#pragma unroll
    for (int s = 0; s < 8; ++s) {
        float b = ((s & 1) ? f[0] : 1.0f - f[0]) *
                  (((s >> 1) & 1) ? f[1] : 1.0f - f[1]) *
                  (((s >> 2) & 1) ? f[2] : 1.0f - f[2]);
        int wi = (lo[0] + (s & 1)) + 25 * (lo[1] + ((s >> 1) & 1)) + 625 * (lo[2] + ((s >> 2) & 1));
        int pos = atomicAdd(&cursor[wi], 1);
        pair_src[pos] = src;
        pair_db[pos] = make_int2(dst, __float_as_int(b));
    }
}

// MFMA conv v9: persistent waves, CONTIGUOUS job ranges (job = bucket*NT +
// slice) so each wave's W reads advance sequentially through memory, plus a
// register prefetch pipeline: next job's 16 W values load during the current
// job's m-loop; m-loop prefetches next tile's src indices. h pre-split into
// bf16 hi/lo planes; b applied post-MFMA; 3 MFMAs/k-tile for ~f32 accuracy.
template <int FIN, int FOUT>
__global__ __launch_bounds__(256) void conv_v9(
    const unsigned short* __restrict__ hhi, const unsigned short* __restrict__ hlo,
    const float* __restrict__ W,
    const int* __restrict__ offsets, const int* __restrict__ pair_src,
    const int2* __restrict__ pair_db, float* __restrict__ agg) {
    constexpr int KT = FIN / 32;   // k-tiles
    constexpr int NT = FOUT / 16;  // col slices per bucket
    const int J = KK * NT;
    int w = threadIdx.x >> 6;
    int lane = threadIdx.x & 63;
    int l15 = lane & 15;
    int lg = lane >> 4;  // 0..3
    int nwaves = gridDim.x * 4;
    int gwave = blockIdx.x * 4 + w;
    int bpw = (J + nwaves - 1) / nwaves;
    int j0 = gwave * bpw;
    int j1 = j0 + bpw < J ? j0 + bpw : J;
    if (j0 >= j1) return;

    float vW[KT * 8];
    auto ldW = [&](int job) {
        int k = job / NT;
        int ns = job - k * NT;
        const float* Wk = W + (size_t)k * (FIN * FOUT) + ns * 16 + l15;
#pragma unroll
        for (int k0 = 0; k0 < KT; ++k0)
#pragma unroll
            for (int i = 0; i < 8; ++i)
                vW[k0 * 8 + i] = Wk[(size_t)(k0 * 32 + lg * 8 + i) * FOUT];
    };

    ldW(j0);
    for (int j = j0; j < j1; ++j) {
        // convert prefetched W -> B fragments (frees vW for next prefetch)
        bf16x8 Bh[KT], Bl[KT];
#pragma unroll
        for (int k0 = 0; k0 < KT; ++k0)
#pragma unroll
            for (int i = 0; i < 8; ++i) {
                float wv = vW[k0 * 8 + i];
                unsigned short hi = bf16rne(wv);
                Bh[k0][i] = (short)hi;
                Bl[k0][i] = (short)bf16rne(wv - bf16tof(hi));
            }
        if (j + 1 < j1) ldW(j + 1);  // next job's W streams during m-loop

        int k = j / NT;
        int nslice = j - k * NT;
        int start = offsets[k];
        int n = offsets[k + 1] - start;
        if (n <= 0) continue;
        const int* psrc = pair_src + start;
        const int2* pdb = pair_db + start;

        int src = psrc[l15 < n ? l15 : 0];
        for (int m0 = 0; m0 < n; m0 += 16) {
            const unsigned short* rhi = hhi + (size_t)src * FIN + lg * 8;
            const unsigned short* rlo = hlo + (size_t)src * FIN + lg * 8;
            // prefetch next tile's src index (independent load)
            int srcn = 0;
            if (m0 + 16 < n) {
                int ra = m0 + 16 + l15;
                srcn = psrc[ra < n ? ra : 0];
            }
            f32x4 acc = (f32x4){0.f, 0.f, 0.f, 0.f};
#pragma unroll
            for (int k0 = 0; k0 < KT; ++k0) {
                bf16x8 Ah = *(const bf16x8*)(rhi + k0 * 32);
                bf16x8 Al = *(const bf16x8*)(rlo + k0 * 32);
                acc = __builtin_amdgcn_mfma_f32_16x16x32_bf16(Ah, Bh[k0], acc, 0, 0, 0);
                acc = __builtin_amdgcn_mfma_f32_16x16x32_bf16(Ah, Bl[k0], acc, 0, 0, 0);
                acc = __builtin_amdgcn_mfma_f32_16x16x32_bf16(Al, Bh[k0], acc, 0, 0, 0);
            }
#pragma unroll
            for (int jj = 0; jj < 4; ++jj) {
                int rm = m0 + lg * 4 + jj;
                if (rm < n) {
                    int2 db = pdb[rm];
                    atomAddF(&agg[(size_t)db.x * FOUT + nslice * 16 + l15],
                             acc[jj] * __int_as_float(db.y));
                }
            }
            src = srcn;
        }
    }
}

// Layer 1 (FIN=2, FOUT=32): f32 input, contiguous bucket ranges.
__global__ __launch_bounds__(256) void conv_l1(
    const float* __restrict__ h, const float* __restrict__ W,
    const int* __restrict__ offsets, const int* __restrict__ pair_src,
    const int2* __restrict__ pair_db, float* __restrict__ agg) {
    int w = threadIdx.x >> 6;
    int lane = threadIdx.x & 63;
    int o = lane & 31;
    int g = lane >> 5;
    int nwaves = gridDim.x * 4;
    int gwave = blockIdx.x * 4 + w;
    int bpw = (KK + nwaves - 1) / nwaves;
    int k0 = gwave * bpw;
    int k1 = k0 + bpw < KK ? k0 + bpw : KK;
    const float2* h2 = (const float2*)h;
    for (int k = k0; k < k1; ++k) {
        int start = offsets[k];
        int n = offsets[k + 1] - start;
        if (n <= 0) continue;
        const float* Wk = W + (size_t)k * 64;
        float w0 = Wk[o], w1 = Wk[32 + o];
        for (int r = g; r < n; r += 2) {
            int src = pair_src[start + r];
            int2 db = pair_db[start + r];
            float b = __int_as_float(db.y);
            float2 xv = h2[src];
            atomAddF(&agg[(size_t)db.x * 32 + o], b * (xv.x * w0 + xv.y * w1));
        }
    }
}

// Layer 5 (FIN=32, FOUT=1): planes input, half-wave per row, shuffle reduce.
__global__ __launch_bounds__(256) void conv_f1(
    const unsigned short* __restrict__ hhi, const unsigned short* __restrict__ hlo,
    const float* __restrict__ W,
    const int* __restrict__ offsets, const int* __restrict__ pair_src,
    const int2* __restrict__ pair_db, float* __restrict__ agg) {
    int w = threadIdx.x >> 6;
    int lane = threadIdx.x & 63;
    int i = lane & 31;
    int g = lane >> 5;
    int nwaves = gridDim.x * 4;
    int gwave = blockIdx.x * 4 + w;
    int bpw = (KK + nwaves - 1) / nwaves;
    int kk0 = gwave * bpw;
    int kk1 = kk0 + bpw < KK ? kk0 + bpw : KK;
    for (int k = kk0; k < kk1; ++k) {
        int start = offsets[k];
        int n = offsets[k + 1] - start;
        if (n <= 0) continue;
        float wk = W[(size_t)k * 32 + i];
        for (int r = g; r < n; r += 2) {
            int src = pair_src[start + r];
            int2 db = pair_db[start + r];
            float b = __int_as_float(db.y);
            float hv = bf16tof(hhi[(size_t)src * 32 + i]) + bf16tof(hlo[(size_t)src * 32 + i]);
            float val = hv * wk * b;
#pragma unroll
            for (int d = 16; d >= 1; d >>= 1) val += __shfl_xor(val, d, 32);
            if (i == 0) atomAddF(&agg[db.x], val);
        }
    }
}

// Node 1: f32 h (FIN=2) -> planes out (FOUT=32). Zeros agg.
__global__ void node1_kernel(const float* __restrict__ h, float* __restrict__ agg,
                             const float* __restrict__ root, const float* __restrict__ bias,
                             unsigned short* __restrict__ ohi, unsigned short* __restrict__ olo) {
    int idx = blockIdx.x * blockDim.x + threadIdx.x;
    if (idx >= NV * 64) return;
    if (idx < NV * 32) {
        int n = idx >> 5, o = idx & 31;
        float acc = agg[idx] + bias[o] + h[n * 2] * root[o] + h[n * 2 + 1] * root[32 + o];
        float v = acc > 0.0f ? acc : expm1f(acc);
        unsigned short hi = bf16rne(v);
        ohi[idx] = hi;
        olo[idx] = bf16rne(v - bf16tof(hi));
    }
    agg[idx] = 0.0f;
}

// Generic node: planes in (FIN) -> planes out (FOUT). Zeros agg.
template <int FIN, int FOUT>
__global__ void node_p(const unsigned short* __restrict__ hhi,
                       const unsigned short* __restrict__ hlo, float* __restrict__ agg,
                       const float* __restrict__ root, const float* __restrict__ bias,
                       unsigned short* __restrict__ ohi, unsigned short* __restrict__ olo) {
    int idx = blockIdx.x * blockDim.x + threadIdx.x;
    if (idx >= NV * 64) return;
    if (idx < NV * FOUT) {
        int n = idx / FOUT, o = idx % FOUT;
        float acc = agg[idx] + bias[o];
#pragma unroll
        for (int i = 0; i < FIN; ++i) {
            float hv = bf16tof(hhi[(size_t)n * FIN + i]) + bf16tof(hlo[(size_t)n * FIN + i]);
            acc += hv * root[i * FOUT + o];
        }
        float v = acc > 0.0f ? acc : expm1f(acc);
        unsigned short hi = bf16rne(v);
        ohi[idx] = hi;
        olo[idx] = bf16rne(v - bf16tof(hi));
    }
    agg[idx] = 0.0f;
}

// Node 5: planes in (FIN=32), agg scalars -> f32 out.
__global__ void node5_kernel(const unsigned short* __restrict__ hhi,
                             const unsigned short* __restrict__ hlo,
                             const float* __restrict__ agg, const float* __restrict__ root,
                             const float* __restrict__ bias, float* __restrict__ out) {
    int n = blockIdx.x * blockDim.x + threadIdx.x;
    if (n >= NV) return;
    float acc = agg[n] + bias[0];
#pragma unroll
    for (int i = 0; i < 32; ++i) {
        float hv = bf16tof(hhi[(size_t)n * 32 + i]) + bf16tof(hlo[(size_t)n * 32 + i]);
        acc += hv * root[i];
    }
    out[n] = acc > 0.0f ? acc : expm1f(acc);
}

extern "C" void kernel_launch(void* const* d_in, const int* in_sizes, int n_in,
                              void* d_out, int out_size, void* d_ws, size_t ws_size,
                              hipStream_t stream) {
    const float* x      = (const float*)d_in[0];
    const int*   ei     = (const int*)d_in[1];
    const float* pseudo = (const float*)d_in[2];
    const float* W1 = (const float*)d_in[3];
    const float* r1 = (const float*)d_in[4];
    const float* b1 = (const float*)d_in[5];
    const float* W2 = (const float*)d_in[6];
    const float* r2 = (const float*)d_in[7];
    const float* b2 = (const float*)d_in[8];
    const float* W3 = (const float*)d_in[9];
    const float* r3 = (const float*)d_in[10];
    const float* b3 = (const float*)d_in[11];
    const float* W4 = (const float*)d_in[12];
    const float* r4 = (const float*)d_in[13];
    const float* b4 = (const float*)d_in[14];
    const float* W5 = (const float*)d_in[15];
    const float* r5 = (const float*)d_in[16];
    const float* b5 = (const float*)d_in[17];

    char* ws = (char*)d_ws;
    size_t off = 0;
    auto alloc = [&](size_t bytes) {
        void* p = ws + off;
        off += (bytes + 255) & ~(size_t)255;
        return p;
    };
    int*   counts   = (int*)alloc(KK * sizeof(int));
    int*   offsets  = (int*)alloc((KK + 1) * sizeof(int));
    int*   cursor   = (int*)alloc(KK * sizeof(int));
    int*   pair_src = (int*)alloc((size_t)EV * 8 * sizeof(int));
    int2*  pair_db  = (int2*)alloc((size_t)EV * 8 * sizeof(int2));
    float* h0       = (float*)alloc((size_t)NV * 2 * sizeof(float));
    unsigned short* pAhi = (unsigned short*)alloc((size_t)NV * 64 * sizeof(unsigned short));
    unsigned short* pAlo = (unsigned short*)alloc((size_t)NV * 64 * sizeof(unsigned short));
    unsigned short* pBhi = (unsigned short*)alloc((size_t)NV * 64 * sizeof(unsigned short));
    unsigned short* pBlo = (unsigned short*)alloc((size_t)NV * 64 * sizeof(unsigned short));
    float* agg      = (float*)alloc((size_t)NV * 64 * sizeof(float));

    const int NGRID = (NV * 64 + 255) / 256;  // 2048
    const int CGRID = 2048;                   // persistent conv grid

    prep_kernel<<<NGRID, 256, 0, stream>>>(x, h0, counts, agg);
    hist_kernel<<<(EV + 255) / 256, 256, 0, stream>>>(pseudo, counts);
    scan_kernel<<<1, 256, 0, stream>>>(counts, offsets, cursor);
    scatter_kernel<<<(EV + 255) / 256, 256, 0, stream>>>(pseudo, ei, cursor, pair_src, pair_db);

    // Layer 1: [N,2] -> [N,32]   (h0 f32 -> planes A)
    conv_l1<<<CGRID, 256, 0, stream>>>(h0, W1, offsets, pair_src, pair_db, agg);
    node1_kernel<<<NGRID, 256, 0, stream>>>(h0, agg, r1, b1, pAhi, pAlo);

    // Layer 2: [N,32] -> [N,64]  (planes A -> planes B)
    conv_v9<32, 64><<<CGRID, 256, 0, stream>>>(pAhi, pAlo, W2, offsets, pair_src, pair_db, agg);
    node_p<32, 64><<<NGRID, 256, 0, stream>>>(pAhi, pAlo, agg, r2, b2, pBhi, pBlo);

    // Layer 3: [N,64] -> [N,64]  (planes B -> planes A)
    conv_v9<64, 64><<<CGRID, 256, 0, stream>>>(pBhi, pBlo, W3, offsets, pair_src, pair_db, agg);
    node_p<64, 64><<<NGRID, 256, 0, stream>>>(pBhi, pBlo, agg, r3, b3, pAhi, pAlo);

    // Layer 4: [N,64] -> [N,32]  (planes A -> planes B)
    conv_v9<64, 32><<<CGRID, 256, 0, stream>>>(pAhi, pAlo, W4, offsets, pair_src, pair_db, agg);
    node_p<64, 32><<<NGRID, 256, 0, stream>>>(pAhi, pAlo, agg, r4, b4, pBhi, pBlo);

    // Layer 5: [N,32] -> [N,1]   (planes B -> d_out)
    conv_f1<<<CGRID, 256, 0, stream>>>(pBhi, pBlo, W5, offsets, pair_src, pair_db, agg);
    node5_kernel<<<(NV + 255) / 256, 256, 0, stream>>>(pBhi, pBlo, agg, r5, b5, (float*)d_out);
}

// Round 11
// 561.622 us; speedup vs baseline: 1.0580x; 1.0580x over previous
//
#include <hip/hip_runtime.h>
#include <math.h>

// Problem constants (match reference)
#define NV 8192
#define EV 49152
#define KK 15625

typedef __attribute__((ext_vector_type(8))) short bf16x8;
typedef __attribute__((ext_vector_type(4))) float f32x4;

__device__ __forceinline__ void atomAddF(float* p, float v) {
    unsafeAtomicAdd(p, v);  // native global_atomic_add_f32
}

__device__ __forceinline__ unsigned short bf16rne(float x) {
    unsigned u = __float_as_uint(x);
    unsigned r = u + 0x7FFFu + ((u >> 16) & 1u);
    return (unsigned short)(r >> 16);
}
__device__ __forceinline__ float bf16tof(unsigned short h) {
    return __uint_as_float(((unsigned)h) << 16);
}

__device__ __forceinline__ void edge_frac(const float* __restrict__ pseudo, int e,
                                          float f[3], int lo[3]) {
#pragma unroll
    for (int j = 0; j < 3; ++j) {
        float v = pseudo[e * 3 + j] * 24.0f;
        float fl = floorf(v);
        int l = (int)fl;
        l = l < 0 ? 0 : (l > 23 ? 23 : l);
        lo[j] = l;
        f[j] = v - (float)l;
    }
}

// Prep: transform x -> h0, zero counts + agg.
__global__ void prep_kernel(const float* __restrict__ x, float* __restrict__ h0,
                            int* __restrict__ counts, float* __restrict__ agg) {
    int gt = blockIdx.x * blockDim.x + threadIdx.x;  // grid = NV*64 threads
    if (gt < NV) {
        const float LC = -0.22703196f, UC = 0.36853024f;
        const float LM = 1.2585511f, UM = 1.648841f;
        const float R = 10.0f;
        float t0 = (x[gt * 2 + 0] - LC) / (UC - LC) * (2.0f * R) - R;
        float t1 = (x[gt * 2 + 1] - LM) / (UM - LM) * (2.0f * R) - R;
        h0[gt * 2 + 0] = fminf(fmaxf(t0, -R), R);
        h0[gt * 2 + 1] = fminf(fmaxf(t1, -R), R);
    }
    if (gt < KK) counts[gt] = 0;
    if (gt < NV * 64) agg[gt] = 0.0f;
}

__global__ void hist_kernel(const float* __restrict__ pseudo, int* __restrict__ counts) {
    int e = blockIdx.x * blockDim.x + threadIdx.x;
    if (e >= EV) return;
    float f[3]; int lo[3];
    edge_frac(pseudo, e, f, lo);
#pragma unroll
    for (int s = 0; s < 8; ++s) {
        int wi = (lo[0] + (s & 1)) + 25 * (lo[1] + ((s >> 1) & 1)) + 625 * (lo[2] + ((s >> 2) & 1));
        atomicAdd(&counts[wi], 1);
    }
}

// single-block exclusive scan over KK bins
__global__ void scan_kernel(const int* __restrict__ counts, int* __restrict__ offsets,
                            int* __restrict__ cursor) {
    __shared__ int sums[256];
    const int CH = 62;
    int t = threadIdx.x;
    int base = t * CH;
    int s = 0;
    for (int i = 0; i < CH; ++i) {
        int idx = base + i;
        if (idx < KK) s += counts[idx];
    }
    sums[t] = s;
    __syncthreads();
    for (int d = 1; d < 256; d <<= 1) {
        int v = (t >= d) ? sums[t - d] : 0;
        __syncthreads();
        sums[t] += v;
        __syncthreads();
    }
    int run = (t > 0) ? sums[t - 1] : 0;
    for (int i = 0; i < CH; ++i) {
        int idx = base + i;
        if (idx < KK) {
            offsets[idx] = run;
            cursor[idx] = run;
            run += counts[idx];
        }
    }
    if (t == 255) offsets[KK] = run;
}

// Scatter: pair_src (gather side) and pair_db = {dst, b} (scatter side).
__global__ void scatter_kernel(const float* __restrict__ pseudo, const int* __restrict__ ei,
                               int* __restrict__ cursor,
                               int* __restrict__ pair_src, int2* __restrict__ pair_db) {
    int e = blockIdx.x * blockDim.x + threadIdx.x;
    if (e >= EV) return;
    float f[3]; int lo[3];
    edge_frac(pseudo, e, f, lo);
    int src = ei[e];
    int dst = ei[EV + e];
#pragma unroll
    for (int s = 0; s < 8; ++s) {
        float b = ((s & 1) ? f[0] : 1.0f - f[0]) *
                  (((s >> 1) & 1) ? f[1] : 1.0f - f[1]) *
                  (((s >> 2) & 1) ? f[2] : 1.0f - f[2]);
        int wi = (lo[0] + (s & 1)) + 25 * (lo[1] + ((s >> 1) & 1)) + 625 * (lo[2] + ((s >> 2) & 1));
        int pos = atomicAdd(&cursor[wi], 1);
        pair_src[pos] = src;
        pair_db[pos] = make_int2(dst, __float_as_int(b));
    }
}

// MFMA conv v10: block-cooperative COALESCED W staging.
// Each 256-thread block handles BPB buckets per iteration (16 KB of W),
// staged into LDS with float4 fully-sequential loads using the
// issue-early / write-late pipeline: next group's global loads are issued
// before the current group's m-loop so HBM latency hides under compute.
// Waves read their B-fragments from LDS once per bucket. h pre-split into
// bf16 hi/lo planes; b applied post-MFMA; 3 MFMAs/k-tile (~f32 accuracy).
template <int FIN, int FOUT>
__global__ __launch_bounds__(256) void conv_v10(
    const unsigned short* __restrict__ hhi, const unsigned short* __restrict__ hlo,
    const float* __restrict__ W, const int* __restrict__ offsets,
    const int* __restrict__ pair_src, const int2* __restrict__ pair_db,
    float* __restrict__ agg) {
    constexpr int KT = FIN / 32;        // k-tiles
    constexpr int NT = FOUT / 16;       // col slices per bucket
    constexpr int BPB = 4 / NT;         // buckets per block-iteration
    constexpr int WSZ = FIN * FOUT * BPB;  // floats staged (<= 4096 = 16 KB)
    constexpr int NL4 = WSZ / 1024;     // float4 loads per thread (2 or 4)
    __shared__ float wlds[WSZ];
    const float4* Wg4 = (const float4*)W;
    const size_t TOT4 = (size_t)KK * FIN * FOUT / 4;
    int t = threadIdx.x;
    int w = t >> 6, lane = t & 63, l15 = lane & 15, lg = lane >> 4;
    int widx = w / NT;                  // bucket slot within block
    int ns = (w % NT) * 16;             // output col-slice base
    int step = gridDim.x * BPB;
    int iters = (KK + step - 1) / step;

    float4 vst[NL4];
    {
        size_t b4 = (size_t)blockIdx.x * BPB * (FIN * FOUT / 4);
#pragma unroll
        for (int i = 0; i < NL4; ++i) {
            size_t idx = b4 + (size_t)i * 256 + t;
            vst[i] = idx < TOT4 ? Wg4[idx] : make_float4(0.f, 0.f, 0.f, 0.f);
        }
    }

    for (int it = 0; it < iters; ++it) {
        __syncthreads();  // (a) previous group's fragments are all in registers
#pragma unroll
        for (int i = 0; i < NL4; ++i) ((float4*)wlds)[i * 256 + t] = vst[i];
        __syncthreads();  // (b) staged

        int kbase = it * step + blockIdx.x * BPB;
        int kb = kbase + widx;
        bool has = kb < KK;
        bf16x8 Bh[KT], Bl[KT];
        if (has) {
            const float* wl = wlds + widx * (FIN * FOUT) + ns + l15;
#pragma unroll
            for (int k0 = 0; k0 < KT; ++k0)
#pragma unroll
                for (int i = 0; i < 8; ++i) {
                    float wv = wl[(size_t)(k0 * 32 + lg * 8 + i) * FOUT];
                    unsigned short hi = bf16rne(wv);
                    Bh[k0][i] = (short)hi;
                    Bl[k0][i] = (short)bf16rne(wv - bf16tof(hi));
                }
        }
        // issue next group's W loads now; they complete during the m-loop
        if (it + 1 < iters) {
            size_t b4 = ((size_t)(it + 1) * step + (size_t)blockIdx.x * BPB) *
                        (FIN * FOUT / 4);
#pragma unroll
            for (int i = 0; i < NL4; ++i) {
                size_t idx = b4 + (size_t)i * 256 + t;
                vst[i] = idx < TOT4 ? Wg4[idx] : make_float4(0.f, 0.f, 0.f, 0.f);
            }
        }
        if (!has) continue;  // barriers at loop top stay uniform
        int start = offsets[kb];
        int n = offsets[kb + 1] - start;
        if (n <= 0) continue;
        const int* psrc = pair_src + start;
        const int2* pdb = pair_db + start;

        for (int m0 = 0; m0 < n; m0 += 16) {
            int ra = m0 + l15;
            int src = psrc[ra < n ? ra : 0];
            const unsigned short* rhi = hhi + (size_t)src * FIN + lg * 8;
            const unsigned short* rlo = hlo + (size_t)src * FIN + lg * 8;
            f32x4 acc = (f32x4){0.f, 0.f, 0.f, 0.f};
#pragma unroll
            for (int k0 = 0; k0 < KT; ++k0) {
                bf16x8 Ah = *(const bf16x8*)(rhi + k0 * 32);
                bf16x8 Al = *(const bf16x8*)(rlo + k0 * 32);
                acc = __builtin_amdgcn_mfma_f32_16x16x32_bf16(Ah, Bh[k0], acc, 0, 0, 0);
                acc = __builtin_amdgcn_mfma_f32_16x16x32_bf16(Ah, Bl[k0], acc, 0, 0, 0);
                acc = __builtin_amdgcn_mfma_f32_16x16x32_bf16(Al, Bh[k0], acc, 0, 0, 0);
            }
#pragma unroll
            for (int jj = 0; jj < 4; ++jj) {
                int rm = m0 + lg * 4 + jj;
                if (rm < n) {
                    int2 db = pdb[rm];
                    atomAddF(&agg[(size_t)db.x * FOUT + ns + l15],
                             acc[jj] * __int_as_float(db.y));
                }
            }
        }
    }
}

// Layer 1 (FIN=2, FOUT=32): f32 input, grid-stride persistent waves.
__global__ __launch_bounds__(256) void conv_l1(
    const float* __restrict__ h, const float* __restrict__ W,
    const int* __restrict__ offsets, const int* __restrict__ pair_src,
    const int2* __restrict__ pair_db, float* __restrict__ agg) {
    int w = threadIdx.x >> 6;
    int lane = threadIdx.x & 63;
    int o = lane & 31;
    int g = lane >> 5;
    int nwaves = gridDim.x * 4;
    const float2* h2 = (const float2*)h;
    for (int k = blockIdx.x * 4 + w; k < KK; k += nwaves) {
        int start = offsets[k];
        int n = offsets[k + 1] - start;
        if (n <= 0) continue;
        const float* Wk = W + (size_t)k * 64;
        float w0 = Wk[o], w1 = Wk[32 + o];
        for (int r = g; r < n; r += 2) {
            int src = pair_src[start + r];
            int2 db = pair_db[start + r];
            float b = __int_as_float(db.y);
            float2 xv = h2[src];
            atomAddF(&agg[(size_t)db.x * 32 + o], b * (xv.x * w0 + xv.y * w1));
        }
    }
}

// Layer 5 (FIN=32, FOUT=1): planes input, grid-stride, half-wave per row.
__global__ __launch_bounds__(256) void conv_f1(
    const unsigned short* __restrict__ hhi, const unsigned short* __restrict__ hlo,
    const float* __restrict__ W,
    const int* __restrict__ offsets, const int* __restrict__ pair_src,
    const int2* __restrict__ pair_db, float* __restrict__ agg) {
    int w = threadIdx.x >> 6;
    int lane = threadIdx.x & 63;
    int i = lane & 31;
    int g = lane >> 5;
    int nwaves = gridDim.x * 4;
    for (int k = blockIdx.x * 4 + w; k < KK; k += nwaves) {
        int start = offsets[k];
        int n = offsets[k + 1] - start;
        if (n <= 0) continue;
        float wk = W[(size_t)k * 32 + i];
        for (int r = g; r < n; r += 2) {
            int src = pair_src[start + r];
            int2 db = pair_db[start + r];
            float b = __int_as_float(db.y);
            float hv = bf16tof(hhi[(size_t)src * 32 + i]) + bf16tof(hlo[(size_t)src * 32 + i]);
            float val = hv * wk * b;
#pragma unroll
            for (int d = 16; d >= 1; d >>= 1) val += __shfl_xor(val, d, 32);
            if (i == 0) atomAddF(&agg[db.x], val);
        }
    }
}

// Node 1: f32 h (FIN=2) -> planes out (FOUT=32). Zeros agg.
__global__ void node1_kernel(const float* __restrict__ h, float* __restrict__ agg,
                             const float* __restrict__ root, const float* __restrict__ bias,
                             unsigned short* __restrict__ ohi, unsigned short* __restrict__ olo) {
    int idx = blockIdx.x * blockDim.x + threadIdx.x;
    if (idx >= NV * 64) return;
    if (idx < NV * 32) {
        int n = idx >> 5, o = idx & 31;
        float acc = agg[idx] + bias[o] + h[n * 2] * root[o] + h[n * 2 + 1] * root[32 + o];
        float v = acc > 0.0f ? acc : expm1f(acc);
        unsigned short hi = bf16rne(v);
        ohi[idx] = hi;
        olo[idx] = bf16rne(v - bf16tof(hi));
    }
    agg[idx] = 0.0f;
}

// Generic node: planes in (FIN) -> planes out (FOUT). Zeros agg.
template <int FIN, int FOUT>
__global__ void node_p(const unsigned short* __restrict__ hhi,
                       const unsigned short* __restrict__ hlo, float* __restrict__ agg,
                       const float* __restrict__ root, const float* __restrict__ bias,
                       unsigned short* __restrict__ ohi, unsigned short* __restrict__ olo) {
    int idx = blockIdx.x * blockDim.x + threadIdx.x;
    if (idx >= NV * 64) return;
    if (idx < NV * FOUT) {
        int n = idx / FOUT, o = idx % FOUT;
        float acc = agg[idx] + bias[o];
#pragma unroll
        for (int i = 0; i < FIN; ++i) {
            float hv = bf16tof(hhi[(size_t)n * FIN + i]) + bf16tof(hlo[(size_t)n * FIN + i]);
            acc += hv * root[i * FOUT + o];
        }
        float v = acc > 0.0f ? acc : expm1f(acc);
        unsigned short hi = bf16rne(v);
        ohi[idx] = hi;
        olo[idx] = bf16rne(v - bf16tof(hi));
    }
    agg[idx] = 0.0f;
}

// Node 5: planes in (FIN=32), agg scalars -> f32 out.
__global__ void node5_kernel(const unsigned short* __restrict__ hhi,
                             const unsigned short* __restrict__ hlo,
                             const float* __restrict__ agg, const float* __restrict__ root,
                             const float* __restrict__ bias, float* __restrict__ out) {
    int n = blockIdx.x * blockDim.x + threadIdx.x;
    if (n >= NV) return;
    float acc = agg[n] + bias[0];
#pragma unroll
    for (int i = 0; i < 32; ++i) {
        float hv = bf16tof(hhi[(size_t)n * 32 + i]) + bf16tof(hlo[(size_t)n * 32 + i]);
        acc += hv * root[i];
    }
    out[n] = acc > 0.0f ? acc : expm1f(acc);
}

extern "C" void kernel_launch(void* const* d_in, const int* in_sizes, int n_in,
                              void* d_out, int out_size, void* d_ws, size_t ws_size,
                              hipStream_t stream) {
    const float* x      = (const float*)d_in[0];
    const int*   ei     = (const int*)d_in[1];
    const float* pseudo = (const float*)d_in[2];
    const float* W1 = (const float*)d_in[3];
    const float* r1 = (const float*)d_in[4];
    const float* b1 = (const float*)d_in[5];
    const float* W2 = (const float*)d_in[6];
    const float* r2 = (const float*)d_in[7];
    const float* b2 = (const float*)d_in[8];
    const float* W3 = (const float*)d_in[9];
    const float* r3 = (const float*)d_in[10];
    const float* b3 = (const float*)d_in[11];
    const float* W4 = (const float*)d_in[12];
    const float* r4 = (const float*)d_in[13];
    const float* b4 = (const float*)d_in[14];
    const float* W5 = (const float*)d_in[15];
    const float* r5 = (const float*)d_in[16];
    const float* b5 = (const float*)d_in[17];

    char* ws = (char*)d_ws;
    size_t off = 0;
    auto alloc = [&](size_t bytes) {
        void* p = ws + off;
        off += (bytes + 255) & ~(size_t)255;
        return p;
    };
    int*   counts   = (int*)alloc(KK * sizeof(int));
    int*   offsets  = (int*)alloc((KK + 1) * sizeof(int));
    int*   cursor   = (int*)alloc(KK * sizeof(int));
    int*   pair_src = (int*)alloc((size_t)EV * 8 * sizeof(int));
    int2*  pair_db  = (int2*)alloc((size_t)EV * 8 * sizeof(int2));
    float* h0       = (float*)alloc((size_t)NV * 2 * sizeof(float));
    unsigned short* pAhi = (unsigned short*)alloc((size_t)NV * 64 * sizeof(unsigned short));
    unsigned short* pAlo = (unsigned short*)alloc((size_t)NV * 64 * sizeof(unsigned short));
    unsigned short* pBhi = (unsigned short*)alloc((size_t)NV * 64 * sizeof(unsigned short));
    unsigned short* pBlo = (unsigned short*)alloc((size_t)NV * 64 * sizeof(unsigned short));
    float* agg      = (float*)alloc((size_t)NV * 64 * sizeof(float));

    const int NGRID = (NV * 64 + 255) / 256;  // 2048
    const int CGRID = 2048;

    prep_kernel<<<NGRID, 256, 0, stream>>>(x, h0, counts, agg);
    hist_kernel<<<(EV + 255) / 256, 256, 0, stream>>>(pseudo, counts);
    scan_kernel<<<1, 256, 0, stream>>>(counts, offsets, cursor);
    scatter_kernel<<<(EV + 255) / 256, 256, 0, stream>>>(pseudo, ei, cursor, pair_src, pair_db);

    // Layer 1: [N,2] -> [N,32]   (h0 f32 -> planes A)
    conv_l1<<<CGRID, 256, 0, stream>>>(h0, W1, offsets, pair_src, pair_db, agg);
    node1_kernel<<<NGRID, 256, 0, stream>>>(h0, agg, r1, b1, pAhi, pAlo);

    // Layer 2: [N,32] -> [N,64]  (planes A -> planes B)
    conv_v10<32, 64><<<CGRID, 256, 0, stream>>>(pAhi, pAlo, W2, offsets, pair_src, pair_db, agg);
    node_p<32, 64><<<NGRID, 256, 0, stream>>>(pAhi, pAlo, agg, r2, b2, pBhi, pBlo);

    // Layer 3: [N,64] -> [N,64]  (planes B -> planes A)
    conv_v10<64, 64><<<CGRID, 256, 0, stream>>>(pBhi, pBlo, W3, offsets, pair_src, pair_db, agg);
    node_p<64, 64><<<NGRID, 256, 0, stream>>>(pBhi, pBlo, agg, r3, b3, pAhi, pAlo);

    // Layer 4: [N,64] -> [N,32]  (planes A -> planes B)
    conv_v10<64, 32><<<CGRID, 256, 0, stream>>>(pAhi, pAlo, W4, offsets, pair_src, pair_db, agg);
    node_p<64, 32><<<NGRID, 256, 0, stream>>>(pAhi, pAlo, agg, r4, b4, pBhi, pBlo);

    // Layer 5: [N,32] -> [N,1]   (planes B -> d_out)
    conv_f1<<<CGRID, 256, 0, stream>>>(pBhi, pBlo, W5, offsets, pair_src, pair_db, agg);
    node5_kernel<<<(NV + 255) / 256, 256, 0, stream>>>(pBhi, pBlo, agg, r5, b5, (float*)d_out);
}